// Round 4
// baseline (503.495 us; speedup 1.0000x reference)
//
#include <hip/hip_runtime.h>
#include <hip/hip_bf16.h>

typedef unsigned short u16;
typedef unsigned int   u32;
typedef __bf16 bf16x8 __attribute__((ext_vector_type(8)));
typedef float  f32x4  __attribute__((ext_vector_type(4)));
typedef u32    u32x2  __attribute__((ext_vector_type(2)));

#define KPAD 1088
#define SEQ  1104          // padded float2 slots per sequence (zmap2 max = 1098)
#define PI_F 3.14159265358979323846f
#define WAVE_FENCE() asm volatile("s_waitcnt lgkmcnt(0)" ::: "memory")

__device__ __forceinline__ u16 f2bf(float f){
    u32 u = __float_as_uint(f);
    return (u16)((u + 0x7FFFu + ((u >> 16) & 1u)) >> 16);
}
__device__ __forceinline__ float bf2f(u16 v){ return __uint_as_float(((u32)v) << 16); }
// pad: slot = e + (e>>4) + 4*(e>>8). injective on [0,1024); jv (bit8-9) shifts banks by 8.
__device__ __forceinline__ int zmap2(int e){ return e + (e >> 4) + 4*(e >> 8); }

// natural spectral index k -> physical LDS slot after the in-place 3-step FFT
// k = kI + 64*kO, kI = jv + 4*ju  ->  logical kO + 16*ju + 256*jv, then pad
__device__ __forceinline__ int sig(int k){
    k &= 1023;
    int a = (k >> 6) + (((k >> 2) & 15) << 4) + ((k & 3) << 8);
    return zmap2(a);
}

__device__ __forceinline__ float2 cmul(float2 a, float2 b){
    return make_float2(a.x*b.x - a.y*b.y, a.x*b.y + a.y*b.x);
}
__device__ __forceinline__ void fft4v(float2& x0, float2& x1, float2& x2, float2& x3){
    float2 t0 = make_float2(x0.x+x2.x, x0.y+x2.y);
    float2 t1 = make_float2(x0.x-x2.x, x0.y-x2.y);
    float2 t2 = make_float2(x1.x+x3.x, x1.y+x3.y);
    float2 t3 = make_float2(x1.x-x3.x, x1.y-x3.y);
    x0 = make_float2(t0.x+t2.x, t0.y+t2.y);
    x2 = make_float2(t0.x-t2.x, t0.y-t2.y);
    x1 = make_float2(t1.x+t3.y, t1.y-t3.x);
    x3 = make_float2(t1.x-t3.y, t1.y+t3.x);
}
// 16-point DFT, output X[j] at slot tau(j)=((j&3)<<2)|(j>>2)
__device__ __forceinline__ void fft16(float2 a[16]){
    #pragma unroll
    for (int u1 = 0; u1 < 4; ++u1) fft4v(a[u1], a[u1+4], a[u1+8], a[u1+12]);
    const float Cq = 0.70710678118654752f;
    const float c1 = 0.92387953251128674f, s1 = 0.38268343236508977f;
    a[5]  = cmul(a[5],  make_float2(c1, -s1));
    a[6]  = cmul(a[6],  make_float2(Cq, -Cq));
    a[7]  = cmul(a[7],  make_float2(s1, -c1));
    a[9]  = cmul(a[9],  make_float2(Cq, -Cq));
    a[10] = cmul(a[10], make_float2(0.0f, -1.0f));
    a[11] = cmul(a[11], make_float2(-Cq, -Cq));
    a[13] = cmul(a[13], make_float2(s1, -c1));
    a[14] = cmul(a[14], make_float2(-Cq, -Cq));
    a[15] = cmul(a[15], make_float2(-c1, s1));
    #pragma unroll
    for (int ja = 0; ja < 4; ++ja) fft4v(a[4*ja], a[4*ja+1], a[4*ja+2], a[4*ja+3]);
}

// ---- wave-local FFT phases: wave w operates only on Z = Zs + w*SEQ ----
__device__ __forceinline__ void fft_stepB_wave(float2* Z, int lane){
    int nA = lane & 15, jv = lane >> 4;
    float2 a[16];
    #pragma unroll
    for (int u = 0; u < 16; ++u) a[u] = Z[zmap2(nA + 16*u + 256*jv)];
    fft16(a);
    float s_, c_;
    __sincosf(-2.0f*PI_F*(float)(nA*jv)*(1.0f/1024.0f), &s_, &c_);
    float2 tw = make_float2(c_, s_);
    __sincosf(-2.0f*PI_F*(float)nA*(1.0f/256.0f), &s_, &c_);
    float2 st = make_float2(c_, s_);
    #pragma unroll
    for (int ju = 0; ju < 16; ++ju){
        Z[zmap2(nA + 16*ju + 256*jv)] = cmul(a[((ju&3)<<2)|(ju>>2)], tw);
        tw = cmul(tw, st);
    }
}
__device__ __forceinline__ void fft_stepC_wave(float2* Z, int lane){
    int ju = (lane & 63) >> 2, jv = lane & 3;
    float2 a[16];
    #pragma unroll
    for (int nA = 0; nA < 16; ++nA) a[nA] = Z[zmap2(nA + 16*ju + 256*jv)];
    fft16(a);
    #pragma unroll
    for (int kO = 0; kO < 16; ++kO)
        Z[zmap2(kO + 16*ju + 256*jv)] = a[((kO&3)<<2)|(kO>>2)];
}

// ---------------- weight prep ----------------
__global__ __launch_bounds__(256) void prep_w(const float* __restrict__ w1,
                                              const float* __restrict__ w2,
                                              u16* __restrict__ WSW){
    int gid = blockIdx.x * 256 + threadIdx.x;
    int qd = gid >> 12;
    int t  = qd & 1;
    int n  = (qd >> 1) & 7;
    int l  = qd >> 4;
    int rr = gid & 4095;
    int o  = rr >> 6;
    int k  = rr & 63;
    const float* w = l ? w2 : w1;
    WSW[gid] = f2bf(w[((size_t)(t*8 + n)*64 + k)*64 + o]);
}

// Spectrum layout: S[SIDX * KPAD + k], SIDX = (((b*8+c)*8+n)*2+pl)*64 + p_local

__device__ __forceinline__ u16 unpack_one(const float2* Zc, int k, int pl, float sf){
    float2 Zk = Zc[sig(k)], Zm = Zc[sig(1024 - k)];
    float sn_, cs_; __sincosf(PI_F*(float)k*(1.0f/1024.0f), &sn_, &cs_);
    float Er=0.5f*(Zk.x+Zm.x), Ei=0.5f*(Zk.y-Zm.y);
    float Dr=0.5f*(Zk.x-Zm.x), Di=0.5f*(Zk.y+Zm.y);
    float Xr = Er + cs_*Di - sn_*Dr;
    float Xi = Ei - sn_*Di - cs_*Dr;
    return f2bf((pl ? Xi : Xr) * sf);
}

// ---------------- forward rfft(2048) ----------------
__global__ __launch_bounds__(256) void fwd_fft(const float* __restrict__ X,
                                               u16* __restrict__ S){
    __shared__ float2 Zs[4*SEQ];
    int tid = threadIdx.x;
    int blk = blockIdx.x;
    int b = blk >> 10;
    int q = blk & 1023;
    int m8 = q & 7, tq = q >> 3;
    int Q = (tq >> 2)*8 + m8, s4 = tq & 3;
    int col0 = Q*16 + s4*4;
    int p  = col0 >> 3;
    int c0 = col0 & 7;
    int n  = p >> 6, pl_ = p & 63;
    int wave = tid >> 6, lane = tid & 63;

    // fused load + pack + step A (registers), write to LDS
    float2 zz[4][4];   // [v][seq]
    #pragma unroll
    for (int v = 0; v < 4; ++v){
        int pi = tid + 256*v;
        size_t base = ((size_t)(b*2048 + 2*pi)*512 + p)*8 + c0;
        f32x4 ve = *(const f32x4*)(X + base);
        f32x4 vo = *(const f32x4*)(X + base + 4096);
        #pragma unroll
        for (int s = 0; s < 4; ++s) zz[v][s] = make_float2(ve[s], vo[s]);
    }
    {
        int u = (tid >> 4) & 15;
        float s_, c_;
        __sincosf(-2.0f*PI_F*(float)u*(1.0f/64.0f), &s_, &c_);
        float2 tw1 = make_float2(c_, s_);
        float2 tw2 = cmul(tw1, tw1);
        float2 tw3 = cmul(tw2, tw1);
        #pragma unroll
        for (int s = 0; s < 4; ++s){
            float2 x0 = zz[0][s], x1 = zz[1][s], x2 = zz[2][s], x3 = zz[3][s];
            fft4v(x0, x1, x2, x3);
            float2* Z = Zs + s*SEQ;
            Z[zmap2(tid)]     = x0;
            Z[zmap2(tid+256)] = cmul(x1, tw1);
            Z[zmap2(tid+512)] = cmul(x2, tw2);
            Z[zmap2(tid+768)] = cmul(x3, tw3);
        }
    }
    __syncthreads();                 // only cross-wave handoff in this kernel
    float2* Z = Zs + wave*SEQ;       // wave w owns seq w from here on
    fft_stepB_wave(Z, lane);
    WAVE_FENCE();
    fft_stepC_wave(Z, lane);
    WAVE_FENCE();
    // unpack + coalesced store: wave w = channel c0+w, pl = lane>>5
    const float sf = 0.02209708691207961f;     // 1/sqrt(2048)
    int pl = lane >> 5, tr = lane & 31;
    u16* rp = S + (size_t)((((b*8 + (c0+wave))*8 + n)*2 + pl)*64 + pl_)*KPAD;
    for (int kk = tr*2; kk <= 1024; kk += 64){
        u16 w0 = unpack_one(Z, kk, pl, sf);
        if (kk < 1024){
            u16 w1 = unpack_one(Z, kk+1, pl, sf);
            *(u32*)(rp + kk) = (u32)w0 | ((u32)w1 << 16);
        } else {
            rp[kk] = w0;
        }
    }
}

// ---------------- MLP (round-2 proven structure) ----------------
__device__ __forceinline__ bf16x8 fetchB(const u16* mat, int o64, int k64, bool neg){
    const u32x2* pb = (const u32x2*)(mat + o64*68 + k64);
    u32x2 lo = pb[0], hi = pb[1];
    union { u32 u[4]; bf16x8 v; } bt;
    bt.u[0]=lo.x; bt.u[1]=lo.y; bt.u[2]=hi.x; bt.u[3]=hi.y;
    if (neg){ bt.u[0]^=0x80008000u; bt.u[1]^=0x80008000u; bt.u[2]^=0x80008000u; bt.u[3]^=0x80008000u; }
    return bt.v;
}
__device__ __forceinline__ bf16x8 loadU16x8(const u16* pp){
    union { u32 u[4]; bf16x8 v; } t;
    const u32* qq = (const u32*)pp;
    t.u[0]=qq[0]; t.u[1]=qq[1]; t.u[2]=qq[2]; t.u[3]=qq[3];
    return t.v;
}

__global__ __launch_bounds__(256) void mlp_kernel(const u16* __restrict__ WSW,
                                                  const float* __restrict__ b1,
                                                  const float* __restrict__ b2,
                                                  u16* __restrict__ S){
    __shared__ __align__(16) u16 AT[4][64*68];
    __shared__ __align__(16) u16 AS[8448];
    int tid = threadIdx.x;
    int blk = blockIdx.x;
    int n = blk & 7;
    int rest = blk >> 3;               // [0,544) = 32 bc x 17 tiles
    int t17 = rest % 17;
    int bc  = rest / 17;
    int b = bc >> 3, c = bc & 7;
    int k0 = t17 << 6;
    int lane = tid & 63, wv = tid >> 6;
    int lane15 = lane & 15, quad = lane >> 4;

    for (int mi = 0; mi < 4; ++mi){
        const u32* src = (const u32*)(WSW + (size_t)(((mi>>1)*8 + n)*2 + (mi&1))*4096);
        u32* dstm = (u32*)AT[mi];
        for (int d = tid; d < 2048; d += 256){
            int o = d >> 5, kk2 = d & 31;
            dstm[o*34 + kk2] = src[d];
        }
    }
    float bb1[8], bb2v[8];
    #pragma unroll
    for (int nb = 0; nb < 8; ++nb){
        int col = nb*16 + lane15;
        int tt = col >> 6, cc = col & 63;
        bb1[nb]  = b1[tt*512 + n*64 + cc];
        bb2v[nb] = b2[tt*512 + n*64 + cc];
    }
    size_t SB = (size_t)(((b*8 + c)*8 + n)*2)*64;
    {
        int rsub = tid & 31;
        for (int rr = tid >> 5; rr < 128; rr += 8){
            const u16* rp = S + (SB + rr)*KPAD + k0;
            u32 w = *(const u32*)(rp + 2*rsub);
            AS[(2*rsub)*132 + rr]   = (u16)(w & 0xFFFFu);
            AS[(2*rsub+1)*132 + rr] = (u16)(w >> 16);
        }
    }
    __syncthreads();
    // ---- layer 1 ----
    const u16* arow = AS + (wv*16 + lane15)*132;
    bf16x8 afr[4];
    #pragma unroll
    for (int kb = 0; kb < 4; ++kb)
        afr[kb] = loadU16x8(arow + kb*32 + quad*8);
    f32x4 acc[8];
    #pragma unroll
    for (int nb = 0; nb < 8; ++nb){ acc[nb][0]=bb1[nb]; acc[nb][1]=bb1[nb]; acc[nb][2]=bb1[nb]; acc[nb][3]=bb1[nb]; }
    #pragma unroll
    for (int nb = 0; nb < 8; ++nb){
        int o64 = (nb&3)*16 + lane15;
        #pragma unroll
        for (int kb = 0; kb < 4; ++kb){
            int k64 = (kb&1)*32 + quad*8;
            const u16* mat; bool neg = false;
            if (kb < 2) mat = (nb<4) ? AT[0] : AT[1];
            else { if (nb<4){ mat = AT[1]; neg = true; } else mat = AT[0]; }
            acc[nb] = __builtin_amdgcn_mfma_f32_16x16x32_bf16(afr[kb], fetchB(mat,o64,k64,neg), acc[nb], 0,0,0);
        }
    }
    #pragma unroll
    for (int nb = 0; nb < 8; ++nb){
        #pragma unroll
        for (int r4 = 0; r4 < 4; ++r4){
            float xv = acc[nb][r4];
            float u_ = xv * 0.70710678118f;
            float u2 = u_*u_;
            float pg = 1.0f + u2*(-0.333333333f + u2*(0.1f + u2*(-0.0238095238f)));
            float h  = 0.5f * xv * (1.0f + 1.12837916709551f * u_ * pg);
            AS[(wv*16 + quad*4 + r4)*132 + nb*16 + lane15] = f2bf(h);
        }
    }
    // ---- layer 2 ----
    bf16x8 a2[4];
    #pragma unroll
    for (int kb = 0; kb < 4; ++kb)
        a2[kb] = loadU16x8(arow + kb*32 + quad*8);
    f32x4 acc2[8];
    #pragma unroll
    for (int nb = 0; nb < 8; ++nb){ acc2[nb][0]=bb2v[nb]; acc2[nb][1]=bb2v[nb]; acc2[nb][2]=bb2v[nb]; acc2[nb][3]=bb2v[nb]; }
    #pragma unroll
    for (int nb = 0; nb < 8; ++nb){
        int o64 = (nb&3)*16 + lane15;
        #pragma unroll
        for (int kb = 0; kb < 4; ++kb){
            int k64 = (kb&1)*32 + quad*8;
            const u16* mat; bool neg = false;
            if (kb < 2) mat = (nb<4) ? AT[2] : AT[3];
            else { if (nb<4){ mat = AT[3]; neg = true; } else mat = AT[2]; }
            acc2[nb] = __builtin_amdgcn_mfma_f32_16x16x32_bf16(a2[kb], fetchB(mat,o64,k64,neg), acc2[nb], 0,0,0);
        }
    }
    __syncthreads();
    #pragma unroll
    for (int nb = 0; nb < 8; ++nb){
        #pragma unroll
        for (int r4 = 0; r4 < 4; ++r4)
            AS[(nb*16 + lane15)*66 + (wv*16 + quad*4 + r4)] = f2bf(acc2[nb][r4]);
    }
    __syncthreads();
    {
        int rsub = tid & 31;
        int k = k0 + 2*rsub;
        for (int rr = tid >> 5; rr < 128; rr += 8){
            u32 val = *(const u32*)(AS + rr*66 + 2*rsub);
            u16* rp = S + (SB + rr)*KPAD + k0;
            if (k + 1 <= 1024)  *(u32*)(rp + 2*rsub) = val;
            else if (k == 1024) rp[2*rsub] = (u16)(val & 0xFFFFu);
        }
    }
}

// ---------------- inverse irfft(2048) + residual ----------------
// Round-4: restructured so a 64-VGPR budget suffices WITHOUT spills (two
// attribute attempts failed to raise the allocator's 64-reg choice; rounds
// 1-3 showed ~+120 MB scratch round-trip). Liveness plan, max ~56 regs:
//   p1: load packed wR/wI (16 u32)
//   p2: EVEN k only: unpack(16) + mirror-shuffle(16) + combine   [wR/wI live]
//   p3: stepA even quads -> LDS (er/ei die)
//   p4: ODD k: unpack (wR/wI die) + mirror-shuffle + combine
//   p5: stepA odd quads -> LDS
//   stepB / stepC (a[16] = 32 regs, nothing else big live)
//   p6: residual-X load AFTER stepC, BEFORE __syncthreads -> latency hides
//       under the barrier + gather; X regs never co-live with a[16].
// sched_barrier(0) pins the phase boundaries so the scheduler can't re-merge
// the even/odd windows (which would recreate the 64+ pressure).
// Lane l holds k = {2l, 2l+1} + 128*i (i=0..7): even-k mirror of (l,i) lives at
// lane (64-l)&63 reg 7-i (lane 0: own reg 8-i, reg8 = Nyquist); odd-k mirror at
// lane 63-l reg 7-i. stepA quads {q,q+256,q+512,q+768} for q in
// {2l,2l+1,2l+128,2l+129} are lane-local (i-parity split), u = l>>3 (+8).
__global__ __launch_bounds__(256)
__attribute__((amdgpu_waves_per_eu(4, 4)))
void inv_fft(const u16* __restrict__ S,
             const float* __restrict__ X,
             float* __restrict__ OUT){
    __shared__ float2 Zs[4*SEQ];
    int tid = threadIdx.x;
    int blk = blockIdx.x;
    int b = blk >> 10;
    int q = blk & 1023;
    int m8 = q & 7, tq = q >> 3;
    int Q = (tq >> 2)*8 + m8, s4 = tq & 3;
    int col0 = Q*16 + s4*4;
    int p  = col0 >> 3;
    int c0 = col0 & 7;
    int n  = p >> 6, pl_ = p & 63;
    int wave = tid >> 6, lane = tid & 63;

    float2* Z = Zs + wave*SEQ;

    // ---- p1: spectrum -> packed registers ----
    const u16* rpR = S + (size_t)((((b*8 + (c0+wave))*8 + n)*2 + 0)*64 + pl_)*KPAD;
    const u16* rpI = rpR + (size_t)64*KPAD;
    u32 wR[8], wI[8];
    #pragma unroll
    for (int i = 0; i < 8; ++i){
        wR[i] = *(const u32*)(rpR + 2*lane + 128*i);
        wI[i] = *(const u32*)(rpI + 2*lane + 128*i);
    }
    u16 nyq = rpR[1024];               // wave-uniform; only lane 0 consumes it

    // stepA twiddles, shared by both quad sets (12 regs, live through p5)
    float2 twa1, twa2, twa3, twb1, twb2, twb3;
    {
        int u0 = lane >> 3;            // q=2l(+1): u=(q>>4)&15 = l>>3 ; q+128: u+8
        float su_, cu_;
        __sincosf(-2.0f*PI_F*(float)u0*(1.0f/64.0f), &su_, &cu_);
        twa1 = make_float2(cu_, su_);
        twa2 = cmul(twa1, twa1);
        twa3 = cmul(twa2, twa1);
        const float RH = 0.70710678118654752f;
        float2 rot = make_float2(RH, -RH);       // e^{-i*2pi*8/64}
        twb1 = cmul(twa1, rot);
        twb2 = cmul(twb1, twb1);
        twb3 = cmul(twb2, twb1);
    }

    // ---- p2: EVEN k (k = 2*lane + 128*i); wR/wI stay packed ----
    {
        float er[8], ei[8], emr[8], emi[8];
        #pragma unroll
        for (int i = 0; i < 8; ++i){
            er[i] = bf2f((u16)(wR[i] & 0xFFFFu));
            ei[i] = bf2f((u16)(wI[i] & 0xFFFFu));
        }
        if (lane == 0) ei[0] = 0.0f;   // Im Y[0] ignored (matches reference irfft)
        int srcE = (64 - lane) & 63;
        #pragma unroll
        for (int i = 0; i < 8; ++i){
            emr[i] = __shfl(er[7-i], srcE);
            emi[i] = __shfl(ei[7-i], srcE);
        }
        if (lane == 0){                // lane 0 mirrors in-lane: reg 8-i, reg8 = Nyquist
            emr[0] = bf2f(nyq); emi[0] = 0.0f;
            #pragma unroll
            for (int i = 1; i < 8; ++i){ emr[i] = er[8-i]; emi[i] = ei[8-i]; }
        }
        #pragma unroll
        for (int i = 0; i < 8; ++i){
            float s2_, c2_;
            __sincosf(PI_F*(float)(2*lane + 128*i)*(1.0f/1024.0f), &s2_, &c2_);
            float Ex = 0.5f*(er[i] + emr[i]), Ey = 0.5f*(ei[i] - emi[i]);
            float Dx = 0.5f*(er[i] - emr[i]), Dy = 0.5f*(ei[i] + emi[i]);
            float Ox = c2_*Dx - s2_*Dy,      Oy = c2_*Dy + s2_*Dx;
            er[i] = Ex - Oy;  ei[i] = Ey + Ox;
        }
        // ---- p3: stepA even quads -> LDS ----
        #pragma unroll
        for (int j0 = 0; j0 < 2; ++j0){
            float2 t1 = j0 ? twb1 : twa1;
            float2 t2 = j0 ? twb2 : twa2;
            float2 t3 = j0 ? twb3 : twa3;
            int qb = 2*lane + 128*j0;  // elements k = qb + 256t -> reg i = j0 + 2t
            float2 x0 = make_float2(er[j0],   ei[j0]);
            float2 x1 = make_float2(er[j0+2], ei[j0+2]);
            float2 x2 = make_float2(er[j0+4], ei[j0+4]);
            float2 x3 = make_float2(er[j0+6], ei[j0+6]);
            fft4v(x0, x1, x2, x3);
            Z[zmap2(qb)]     = x0;
            Z[zmap2(qb+256)] = cmul(x1, t1);
            Z[zmap2(qb+512)] = cmul(x2, t2);
            Z[zmap2(qb+768)] = cmul(x3, t3);
        }
    }

    __builtin_amdgcn_sched_barrier(0);  // keep odd window out of the even window

    // ---- p4: ODD k (k = 2*lane + 1 + 128*i); wR/wI die here ----
    {
        float odr[8], odi[8], emr[8], emi[8];
        #pragma unroll
        for (int i = 0; i < 8; ++i){
            odr[i] = bf2f((u16)(wR[i] >> 16));
            odi[i] = bf2f((u16)(wI[i] >> 16));
        }
        int srcO = 63 - lane;          // mirror lane always valid, no special case
        #pragma unroll
        for (int i = 0; i < 8; ++i){
            emr[i] = __shfl(odr[7-i], srcO);
            emi[i] = __shfl(odi[7-i], srcO);
        }
        #pragma unroll
        for (int i = 0; i < 8; ++i){
            float s2_, c2_;
            __sincosf(PI_F*(float)(2*lane + 1 + 128*i)*(1.0f/1024.0f), &s2_, &c2_);
            float Ex = 0.5f*(odr[i] + emr[i]), Ey = 0.5f*(odi[i] - emi[i]);
            float Dx = 0.5f*(odr[i] - emr[i]), Dy = 0.5f*(odi[i] + emi[i]);
            float Ox = c2_*Dx - s2_*Dy,        Oy = c2_*Dy + s2_*Dx;
            odr[i] = Ex - Oy;  odi[i] = Ey + Ox;
        }
        // ---- p5: stepA odd quads -> LDS ----
        #pragma unroll
        for (int j0 = 0; j0 < 2; ++j0){
            float2 t1 = j0 ? twb1 : twa1;
            float2 t2 = j0 ? twb2 : twa2;
            float2 t3 = j0 ? twb3 : twa3;
            int qb = 2*lane + 1 + 128*j0;
            float2 x0 = make_float2(odr[j0],   odi[j0]);
            float2 x1 = make_float2(odr[j0+2], odi[j0+2]);
            float2 x2 = make_float2(odr[j0+4], odi[j0+4]);
            float2 x3 = make_float2(odr[j0+6], odi[j0+6]);
            fft4v(x0, x1, x2, x3);
            Z[zmap2(qb)]     = x0;
            Z[zmap2(qb+256)] = cmul(x1, t1);
            Z[zmap2(qb+512)] = cmul(x2, t2);
            Z[zmap2(qb+768)] = cmul(x3, t3);
        }
    }

    WAVE_FENCE();
    fft_stepB_wave(Z, lane);
    WAVE_FENCE();
    fft_stepC_wave(Z, lane);

    // ---- p6: residual-X load; latency hides under barrier + gather ----
    __builtin_amdgcn_sched_barrier(0);  // don't hoist into stepB/stepC (a[16] live there)
    f32x4 xe[4], xo[4];
    #pragma unroll
    for (int i = 0; i < 4; ++i){
        int pi = tid + 256*i;
        size_t base = ((size_t)(b*2048 + 2*pi)*512 + p)*8 + c0;
        xe[i] = *(const f32x4*)(X + base);
        xo[i] = *(const f32x4*)(X + base + 4096);
    }
    __builtin_amdgcn_sched_barrier(0);  // don't sink past the barrier either

    __syncthreads();                 // only cross-wave handoff: final gather reads all 4 seqs
    // unpack (index reversal) + residual + float4 store
    const float sc = 0.04419417382415922f;   // sqrt(2048)/1024
    #pragma unroll
    for (int i = 0; i < 4; ++i){
        int pi = tid + 256*i;
        int zb = sig(1024 - pi);
        size_t base = ((size_t)(b*2048 + 2*pi)*512 + p)*8 + c0;
        f32x4 oe, oo;
        #pragma unroll
        for (int s = 0; s < 4; ++s){
            float2 r = Zs[s*SEQ + zb];
            oe[s] = r.x*sc + xe[i][s];
            oo[s] = r.y*sc + xo[i][s];
        }
        *(f32x4*)(OUT + base)        = oe;
        *(f32x4*)(OUT + base + 4096) = oo;
    }
}

extern "C" void kernel_launch(void* const* d_in, const int* in_sizes, int n_in,
                              void* d_out, int out_size, void* d_ws, size_t ws_size,
                              hipStream_t stream){
    (void)in_sizes; (void)n_in; (void)out_size; (void)ws_size;
    const float* x  = (const float*)d_in[0];
    const float* w1 = (const float*)d_in[1];
    const float* b1 = (const float*)d_in[2];
    const float* w2 = (const float*)d_in[3];
    const float* b2 = (const float*)d_in[4];
    float* out = (float*)d_out;
    u16* WSW = (u16*)d_ws;
    u16* S1  = (u16*)((char*)d_ws + (1 << 20));

    prep_w<<<dim3(512),  dim3(256), 0, stream>>>(w1, w2, WSW);
    fwd_fft<<<dim3(4096), dim3(256), 0, stream>>>(x, S1);
    mlp_kernel<<<dim3(4352), dim3(256), 0, stream>>>(WSW, b1, b2, S1);
    inv_fft<<<dim3(4096), dim3(256), 0, stream>>>(S1, x, out);
}

// Round 6
// 490.841 us; speedup vs baseline: 1.0258x; 1.0258x over previous
//
#include <hip/hip_runtime.h>
#include <hip/hip_bf16.h>

typedef unsigned short u16;
typedef unsigned int   u32;
typedef __bf16 bf16x8 __attribute__((ext_vector_type(8)));
typedef float  f32x4  __attribute__((ext_vector_type(4)));
typedef u32    u32x2  __attribute__((ext_vector_type(2)));

#define KPAD 1088
#define SEQ  1104          // padded float2 slots per sequence (zmap2 max = 1098)
#define PI_F 3.14159265358979323846f
#define WAVE_FENCE() asm volatile("s_waitcnt lgkmcnt(0)" ::: "memory")

__device__ __forceinline__ u16 f2bf(float f){
    u32 u = __float_as_uint(f);
    return (u16)((u + 0x7FFFu + ((u >> 16) & 1u)) >> 16);
}
__device__ __forceinline__ float bf2f(u16 v){ return __uint_as_float(((u32)v) << 16); }
// pad: slot = e + (e>>4) + 4*(e>>8). injective on [0,1024); jv (bit8-9) shifts banks by 8.
__device__ __forceinline__ int zmap2(int e){ return e + (e >> 4) + 4*(e >> 8); }

// natural spectral index k -> physical LDS slot after the in-place 3-step FFT
// k = kI + 64*kO, kI = jv + 4*ju  ->  logical kO + 16*ju + 256*jv, then pad
__device__ __forceinline__ int sig(int k){
    k &= 1023;
    int a = (k >> 6) + (((k >> 2) & 15) << 4) + ((k & 3) << 8);
    return zmap2(a);
}

__device__ __forceinline__ float2 cmul(float2 a, float2 b){
    return make_float2(a.x*b.x - a.y*b.y, a.x*b.y + a.y*b.x);
}
__device__ __forceinline__ void fft4v(float2& x0, float2& x1, float2& x2, float2& x3){
    float2 t0 = make_float2(x0.x+x2.x, x0.y+x2.y);
    float2 t1 = make_float2(x0.x-x2.x, x0.y-x2.y);
    float2 t2 = make_float2(x1.x+x3.x, x1.y+x3.y);
    float2 t3 = make_float2(x1.x-x3.x, x1.y-x3.y);
    x0 = make_float2(t0.x+t2.x, t0.y+t2.y);
    x2 = make_float2(t0.x-t2.x, t0.y-t2.y);
    x1 = make_float2(t1.x+t3.y, t1.y-t3.x);
    x3 = make_float2(t1.x-t3.y, t1.y+t3.x);
}
// 16-point DFT, output X[j] at slot tau(j)=((j&3)<<2)|(j>>2)
__device__ __forceinline__ void fft16(float2 a[16]){
    #pragma unroll
    for (int u1 = 0; u1 < 4; ++u1) fft4v(a[u1], a[u1+4], a[u1+8], a[u1+12]);
    const float Cq = 0.70710678118654752f;
    const float c1 = 0.92387953251128674f, s1 = 0.38268343236508977f;
    a[5]  = cmul(a[5],  make_float2(c1, -s1));
    a[6]  = cmul(a[6],  make_float2(Cq, -Cq));
    a[7]  = cmul(a[7],  make_float2(s1, -c1));
    a[9]  = cmul(a[9],  make_float2(Cq, -Cq));
    a[10] = cmul(a[10], make_float2(0.0f, -1.0f));
    a[11] = cmul(a[11], make_float2(-Cq, -Cq));
    a[13] = cmul(a[13], make_float2(s1, -c1));
    a[14] = cmul(a[14], make_float2(-Cq, -Cq));
    a[15] = cmul(a[15], make_float2(-c1, s1));
    #pragma unroll
    for (int ja = 0; ja < 4; ++ja) fft4v(a[4*ja], a[4*ja+1], a[4*ja+2], a[4*ja+3]);
}

// ---- wave-local FFT phases: wave w operates only on Z = Zs + w*SEQ ----
__device__ __forceinline__ void fft_stepB_wave(float2* Z, int lane){
    int nA = lane & 15, jv = lane >> 4;
    float2 a[16];
    #pragma unroll
    for (int u = 0; u < 16; ++u) a[u] = Z[zmap2(nA + 16*u + 256*jv)];
    fft16(a);
    float s_, c_;
    __sincosf(-2.0f*PI_F*(float)(nA*jv)*(1.0f/1024.0f), &s_, &c_);
    float2 tw = make_float2(c_, s_);
    __sincosf(-2.0f*PI_F*(float)nA*(1.0f/256.0f), &s_, &c_);
    float2 st = make_float2(c_, s_);
    #pragma unroll
    for (int ju = 0; ju < 16; ++ju){
        Z[zmap2(nA + 16*ju + 256*jv)] = cmul(a[((ju&3)<<2)|(ju>>2)], tw);
        tw = cmul(tw, st);
    }
}
__device__ __forceinline__ void fft_stepC_wave(float2* Z, int lane){
    int ju = (lane & 63) >> 2, jv = lane & 3;
    float2 a[16];
    #pragma unroll
    for (int nA = 0; nA < 16; ++nA) a[nA] = Z[zmap2(nA + 16*ju + 256*jv)];
    fft16(a);
    #pragma unroll
    for (int kO = 0; kO < 16; ++kO)
        Z[zmap2(kO + 16*ju + 256*jv)] = a[((kO&3)<<2)|(kO>>2)];
}

// ---------------- weight prep ----------------
__global__ __launch_bounds__(256) void prep_w(const float* __restrict__ w1,
                                              const float* __restrict__ w2,
                                              u16* __restrict__ WSW){
    int gid = blockIdx.x * 256 + threadIdx.x;
    int qd = gid >> 12;
    int t  = qd & 1;
    int n  = (qd >> 1) & 7;
    int l  = qd >> 4;
    int rr = gid & 4095;
    int o  = rr >> 6;
    int k  = rr & 63;
    const float* w = l ? w2 : w1;
    WSW[gid] = f2bf(w[((size_t)(t*8 + n)*64 + k)*64 + o]);
}

// Spectrum layout: S[SIDX * KPAD + k], SIDX = (((b*8+c)*8+n)*2+pl)*64 + p_local

__device__ __forceinline__ u16 unpack_one(const float2* Zc, int k, int pl, float sf){
    float2 Zk = Zc[sig(k)], Zm = Zc[sig(1024 - k)];
    float sn_, cs_; __sincosf(PI_F*(float)k*(1.0f/1024.0f), &sn_, &cs_);
    float Er=0.5f*(Zk.x+Zm.x), Ei=0.5f*(Zk.y-Zm.y);
    float Dr=0.5f*(Zk.x-Zm.x), Di=0.5f*(Zk.y+Zm.y);
    float Xr = Er + cs_*Di - sn_*Dr;
    float Xi = Ei - sn_*Di - cs_*Dr;
    return f2bf((pl ? Xi : Xr) * sf);
}

// ---------------- forward rfft(2048) ----------------
__global__ __launch_bounds__(256) void fwd_fft(const float* __restrict__ X,
                                               u16* __restrict__ S){
    __shared__ float2 Zs[4*SEQ];
    int tid = threadIdx.x;
    int blk = blockIdx.x;
    int b = blk >> 10;
    int q = blk & 1023;
    int m8 = q & 7, tq = q >> 3;
    int Q = (tq >> 2)*8 + m8, s4 = tq & 3;
    int col0 = Q*16 + s4*4;
    int p  = col0 >> 3;
    int c0 = col0 & 7;
    int n  = p >> 6, pl_ = p & 63;
    int wave = tid >> 6, lane = tid & 63;

    // fused load + pack + step A (registers), write to LDS
    float2 zz[4][4];   // [v][seq]
    #pragma unroll
    for (int v = 0; v < 4; ++v){
        int pi = tid + 256*v;
        size_t base = ((size_t)(b*2048 + 2*pi)*512 + p)*8 + c0;
        f32x4 ve = *(const f32x4*)(X + base);
        f32x4 vo = *(const f32x4*)(X + base + 4096);
        #pragma unroll
        for (int s = 0; s < 4; ++s) zz[v][s] = make_float2(ve[s], vo[s]);
    }
    {
        int u = (tid >> 4) & 15;
        float s_, c_;
        __sincosf(-2.0f*PI_F*(float)u*(1.0f/64.0f), &s_, &c_);
        float2 tw1 = make_float2(c_, s_);
        float2 tw2 = cmul(tw1, tw1);
        float2 tw3 = cmul(tw2, tw1);
        #pragma unroll
        for (int s = 0; s < 4; ++s){
            float2 x0 = zz[0][s], x1 = zz[1][s], x2 = zz[2][s], x3 = zz[3][s];
            fft4v(x0, x1, x2, x3);
            float2* Z = Zs + s*SEQ;
            Z[zmap2(tid)]     = x0;
            Z[zmap2(tid+256)] = cmul(x1, tw1);
            Z[zmap2(tid+512)] = cmul(x2, tw2);
            Z[zmap2(tid+768)] = cmul(x3, tw3);
        }
    }
    __syncthreads();                 // only cross-wave handoff in this kernel
    float2* Z = Zs + wave*SEQ;       // wave w owns seq w from here on
    fft_stepB_wave(Z, lane);
    WAVE_FENCE();
    fft_stepC_wave(Z, lane);
    WAVE_FENCE();
    // unpack + coalesced store: wave w = channel c0+w, pl = lane>>5
    const float sf = 0.02209708691207961f;     // 1/sqrt(2048)
    int pl = lane >> 5, tr = lane & 31;
    u16* rp = S + (size_t)((((b*8 + (c0+wave))*8 + n)*2 + pl)*64 + pl_)*KPAD;
    for (int kk = tr*2; kk <= 1024; kk += 64){
        u16 w0 = unpack_one(Z, kk, pl, sf);
        if (kk < 1024){
            u16 w1 = unpack_one(Z, kk+1, pl, sf);
            *(u32*)(rp + kk) = (u32)w0 | ((u32)w1 << 16);
        } else {
            rp[kk] = w0;
        }
    }
}

// ---------------- MLP (round-2 proven structure) ----------------
__device__ __forceinline__ bf16x8 fetchB(const u16* mat, int o64, int k64, bool neg){
    const u32x2* pb = (const u32x2*)(mat + o64*68 + k64);
    u32x2 lo = pb[0], hi = pb[1];
    union { u32 u[4]; bf16x8 v; } bt;
    bt.u[0]=lo.x; bt.u[1]=lo.y; bt.u[2]=hi.x; bt.u[3]=hi.y;
    if (neg){ bt.u[0]^=0x80008000u; bt.u[1]^=0x80008000u; bt.u[2]^=0x80008000u; bt.u[3]^=0x80008000u; }
    return bt.v;
}
__device__ __forceinline__ bf16x8 loadU16x8(const u16* pp){
    union { u32 u[4]; bf16x8 v; } t;
    const u32* qq = (const u32*)pp;
    t.u[0]=qq[0]; t.u[1]=qq[1]; t.u[2]=qq[2]; t.u[3]=qq[3];
    return t.v;
}

__global__ __launch_bounds__(256) void mlp_kernel(const u16* __restrict__ WSW,
                                                  const float* __restrict__ b1,
                                                  const float* __restrict__ b2,
                                                  u16* __restrict__ S){
    __shared__ __align__(16) u16 AT[4][64*68];
    __shared__ __align__(16) u16 AS[8448];
    int tid = threadIdx.x;
    int blk = blockIdx.x;
    int n = blk & 7;
    int rest = blk >> 3;               // [0,544) = 32 bc x 17 tiles
    int t17 = rest % 17;
    int bc  = rest / 17;
    int b = bc >> 3, c = bc & 7;
    int k0 = t17 << 6;
    int lane = tid & 63, wv = tid >> 6;
    int lane15 = lane & 15, quad = lane >> 4;

    for (int mi = 0; mi < 4; ++mi){
        const u32* src = (const u32*)(WSW + (size_t)(((mi>>1)*8 + n)*2 + (mi&1))*4096);
        u32* dstm = (u32*)AT[mi];
        for (int d = tid; d < 2048; d += 256){
            int o = d >> 5, kk2 = d & 31;
            dstm[o*34 + kk2] = src[d];
        }
    }
    float bb1[8], bb2v[8];
    #pragma unroll
    for (int nb = 0; nb < 8; ++nb){
        int col = nb*16 + lane15;
        int tt = col >> 6, cc = col & 63;
        bb1[nb]  = b1[tt*512 + n*64 + cc];
        bb2v[nb] = b2[tt*512 + n*64 + cc];
    }
    size_t SB = (size_t)(((b*8 + c)*8 + n)*2)*64;
    {
        int rsub = tid & 31;
        for (int rr = tid >> 5; rr < 128; rr += 8){
            const u16* rp = S + (SB + rr)*KPAD + k0;
            u32 w = *(const u32*)(rp + 2*rsub);
            AS[(2*rsub)*132 + rr]   = (u16)(w & 0xFFFFu);
            AS[(2*rsub+1)*132 + rr] = (u16)(w >> 16);
        }
    }
    __syncthreads();
    // ---- layer 1 ----
    const u16* arow = AS + (wv*16 + lane15)*132;
    bf16x8 afr[4];
    #pragma unroll
    for (int kb = 0; kb < 4; ++kb)
        afr[kb] = loadU16x8(arow + kb*32 + quad*8);
    f32x4 acc[8];
    #pragma unroll
    for (int nb = 0; nb < 8; ++nb){ acc[nb][0]=bb1[nb]; acc[nb][1]=bb1[nb]; acc[nb][2]=bb1[nb]; acc[nb][3]=bb1[nb]; }
    #pragma unroll
    for (int nb = 0; nb < 8; ++nb){
        int o64 = (nb&3)*16 + lane15;
        #pragma unroll
        for (int kb = 0; kb < 4; ++kb){
            int k64 = (kb&1)*32 + quad*8;
            const u16* mat; bool neg = false;
            if (kb < 2) mat = (nb<4) ? AT[0] : AT[1];
            else { if (nb<4){ mat = AT[1]; neg = true; } else mat = AT[0]; }
            acc[nb] = __builtin_amdgcn_mfma_f32_16x16x32_bf16(afr[kb], fetchB(mat,o64,k64,neg), acc[nb], 0,0,0);
        }
    }
    #pragma unroll
    for (int nb = 0; nb < 8; ++nb){
        #pragma unroll
        for (int r4 = 0; r4 < 4; ++r4){
            float xv = acc[nb][r4];
            float u_ = xv * 0.70710678118f;
            float u2 = u_*u_;
            float pg = 1.0f + u2*(-0.333333333f + u2*(0.1f + u2*(-0.0238095238f)));
            float h  = 0.5f * xv * (1.0f + 1.12837916709551f * u_ * pg);
            AS[(wv*16 + quad*4 + r4)*132 + nb*16 + lane15] = f2bf(h);
        }
    }
    // ---- layer 2 ----
    bf16x8 a2[4];
    #pragma unroll
    for (int kb = 0; kb < 4; ++kb)
        a2[kb] = loadU16x8(arow + kb*32 + quad*8);
    f32x4 acc2[8];
    #pragma unroll
    for (int nb = 0; nb < 8; ++nb){ acc2[nb][0]=bb2v[nb]; acc2[nb][1]=bb2v[nb]; acc2[nb][2]=bb2v[nb]; acc2[nb][3]=bb2v[nb]; }
    #pragma unroll
    for (int nb = 0; nb < 8; ++nb){
        int o64 = (nb&3)*16 + lane15;
        #pragma unroll
        for (int kb = 0; kb < 4; ++kb){
            int k64 = (kb&1)*32 + quad*8;
            const u16* mat; bool neg = false;
            if (kb < 2) mat = (nb<4) ? AT[2] : AT[3];
            else { if (nb<4){ mat = AT[3]; neg = true; } else mat = AT[2]; }
            acc2[nb] = __builtin_amdgcn_mfma_f32_16x16x32_bf16(a2[kb], fetchB(mat,o64,k64,neg), acc2[nb], 0,0,0);
        }
    }
    __syncthreads();
    #pragma unroll
    for (int nb = 0; nb < 8; ++nb){
        #pragma unroll
        for (int r4 = 0; r4 < 4; ++r4)
            AS[(nb*16 + lane15)*66 + (wv*16 + quad*4 + r4)] = f2bf(acc2[nb][r4]);
    }
    __syncthreads();
    {
        int rsub = tid & 31;
        int k = k0 + 2*rsub;
        for (int rr = tid >> 5; rr < 128; rr += 8){
            u32 val = *(const u32*)(AS + rr*66 + 2*rsub);
            u16* rp = S + (SB + rr)*KPAD + k0;
            if (k + 1 <= 1024)  *(u32*)(rp + 2*rsub) = val;
            else if (k == 1024) rp[2*rsub] = (u16)(val & 0xFFFFu);
        }
    }
}

// ---------------- inverse irfft(2048) + residual ----------------
// Round-5 (resubmit; round-5 run died to container infra, no kernel signal).
// Odd-half LDS stash kills the long-lived packed state. Rounds 1-4 spilled
// because the odd-k halves of wR/wI (16 u32) had to stay live across the
// whole even-k window (32 regs) -> >60-reg peak. Now the odd halves are
// re-packed and stashed in the 8 odd-k stepA-OUTPUT slots of this lane (LDS
// that p5 will overwrite anyway): wR/wI die immediately after the even
// unpack. Max live window ~52 regs, fits the 64-reg budget w/o spills.
//   p1  : load packed wR/wI (16 u32) + nyquist
//   p1.5: od_packed[i] = (wR>>16)|(wI&0xFFFF0000) -> stash to odd slots; wR/wI die
//   p2  : even unpack + mirror-shuffle + hermitian combine (peak 32+temps)
//   p3  : twiddles + stepA even quads -> LDS even slots
//   p4  : read back odd stash + mirror-shuffle + combine (peak 44+temps)
//   p5  : stepA odd quads -> LDS odd slots (overwrites stash)
//   stepB/stepC, then p6: residual-X load (hides under barrier+gather)
// Lane l holds k = {2l, 2l+1} + 128*i (i=0..7): even-k mirror of (l,i) lives at
// lane (64-l)&63 reg 7-i (lane 0: own reg 8-i, reg8 = Nyquist); odd-k mirror at
// lane 63-l reg 7-i. stepA quads {q,q+256,q+512,q+768} for q in
// {2l,2l+1,2l+128,2l+129} are lane-local (i-parity split), u = l>>3 (+8).
__global__ __launch_bounds__(256) void inv_fft(const u16* __restrict__ S,
                                               const float* __restrict__ X,
                                               float* __restrict__ OUT){
    __shared__ float2 Zs[4*SEQ];
    int tid = threadIdx.x;
    int blk = blockIdx.x;
    int b = blk >> 10;
    int q = blk & 1023;
    int m8 = q & 7, tq = q >> 3;
    int Q = (tq >> 2)*8 + m8, s4 = tq & 3;
    int col0 = Q*16 + s4*4;
    int p  = col0 >> 3;
    int c0 = col0 & 7;
    int n  = p >> 6, pl_ = p & 63;
    int wave = tid >> 6, lane = tid & 63;

    float2* Z = Zs + wave*SEQ;

    // ---- p1: spectrum -> packed registers ----
    const u16* rpR = S + (size_t)((((b*8 + (c0+wave))*8 + n)*2 + 0)*64 + pl_)*KPAD;
    const u16* rpI = rpR + (size_t)64*KPAD;
    u32 wR[8], wI[8];
    #pragma unroll
    for (int i = 0; i < 8; ++i){
        wR[i] = *(const u32*)(rpR + 2*lane + 128*i);
        wI[i] = *(const u32*)(rpI + 2*lane + 128*i);
    }
    u16 nyq = rpR[1024];               // wave-uniform; only lane 0 consumes it

    // ---- p1.5: stash odd halves into this lane's odd stepA-output slots ----
    // slot(i) = zmap2(2l+1 + 128*(i&1) + 256*(i>>1))  (exactly what p5 overwrites)
    #pragma unroll
    for (int i = 0; i < 8; ++i){
        u32 od = (wR[i] >> 16) | (wI[i] & 0xFFFF0000u);
        Z[zmap2(2*lane + 1 + 128*(i&1) + 256*(i>>1))].x = __uint_as_float(od);
    }

    // ---- p2: even unpack + hermitian combine; wR/wI die at the unpack ----
    float er[8], ei[8];
    #pragma unroll
    for (int i = 0; i < 8; ++i){
        er[i] = bf2f((u16)(wR[i] & 0xFFFFu));
        ei[i] = bf2f((u16)(wI[i] & 0xFFFFu));
    }
    if (lane == 0) ei[0] = 0.0f;       // Im Y[0] ignored (matches reference irfft)
    {
        float emr[8], emi[8];
        int srcE = (64 - lane) & 63;
        #pragma unroll
        for (int i = 0; i < 8; ++i){
            emr[i] = __shfl(er[7-i], srcE);
            emi[i] = __shfl(ei[7-i], srcE);
        }
        if (lane == 0){                // lane 0 mirrors in-lane: reg 8-i, reg8 = Nyquist
            emr[0] = bf2f(nyq); emi[0] = 0.0f;
            #pragma unroll
            for (int i = 1; i < 8; ++i){ emr[i] = er[8-i]; emi[i] = ei[8-i]; }
        }
        #pragma unroll
        for (int i = 0; i < 8; ++i){
            float s2_, c2_;
            __sincosf(PI_F*(float)(2*lane + 128*i)*(1.0f/1024.0f), &s2_, &c2_);
            float Ex = 0.5f*(er[i] + emr[i]), Ey = 0.5f*(ei[i] - emi[i]);
            float Dx = 0.5f*(er[i] - emr[i]), Dy = 0.5f*(ei[i] + emi[i]);
            float Ox = c2_*Dx - s2_*Dy,      Oy = c2_*Dy + s2_*Dx;
            er[i] = Ex - Oy;  ei[i] = Ey + Ox;
        }
    }

    // ---- p3: stepA twiddles + even quads -> LDS ----
    float2 twa1, twa2, twa3, twb1, twb2, twb3;
    {
        int u0 = lane >> 3;            // q=2l(+1): u=(q>>4)&15 = l>>3 ; q+128: u+8
        float su_, cu_;
        __sincosf(-2.0f*PI_F*(float)u0*(1.0f/64.0f), &su_, &cu_);
        twa1 = make_float2(cu_, su_);
        twa2 = cmul(twa1, twa1);
        twa3 = cmul(twa2, twa1);
        const float RH = 0.70710678118654752f;
        float2 rot = make_float2(RH, -RH);       // e^{-i*2pi*8/64}
        twb1 = cmul(twa1, rot);
        twb2 = cmul(twb1, twb1);
        twb3 = cmul(twb2, twb1);
    }
    #pragma unroll
    for (int j0 = 0; j0 < 2; ++j0){
        float2 t1 = j0 ? twb1 : twa1;
        float2 t2 = j0 ? twb2 : twa2;
        float2 t3 = j0 ? twb3 : twa3;
        int qb = 2*lane + 128*j0;      // elements k = qb + 256t -> reg i = j0 + 2t
        float2 x0 = make_float2(er[j0],   ei[j0]);
        float2 x1 = make_float2(er[j0+2], ei[j0+2]);
        float2 x2 = make_float2(er[j0+4], ei[j0+4]);
        float2 x3 = make_float2(er[j0+6], ei[j0+6]);
        fft4v(x0, x1, x2, x3);
        Z[zmap2(qb)]     = x0;
        Z[zmap2(qb+256)] = cmul(x1, t1);
        Z[zmap2(qb+512)] = cmul(x2, t2);
        Z[zmap2(qb+768)] = cmul(x3, t3);
    }

    // ---- p4: odd readback + hermitian combine ----
    WAVE_FENCE();                      // stash writes definitely complete
    float odr[8], odi[8];
    #pragma unroll
    for (int i = 0; i < 8; ++i){
        u32 od = __float_as_uint(Z[zmap2(2*lane + 1 + 128*(i&1) + 256*(i>>1))].x);
        odr[i] = bf2f((u16)(od & 0xFFFFu));
        odi[i] = bf2f((u16)(od >> 16));
    }
    {
        float emr[8], emi[8];
        int srcO = 63 - lane;          // mirror lane always valid, no special case
        #pragma unroll
        for (int i = 0; i < 8; ++i){
            emr[i] = __shfl(odr[7-i], srcO);
            emi[i] = __shfl(odi[7-i], srcO);
        }
        #pragma unroll
        for (int i = 0; i < 8; ++i){
            float s2_, c2_;
            __sincosf(PI_F*(float)(2*lane + 1 + 128*i)*(1.0f/1024.0f), &s2_, &c2_);
            float Ex = 0.5f*(odr[i] + emr[i]), Ey = 0.5f*(odi[i] - emi[i]);
            float Dx = 0.5f*(odr[i] - emr[i]), Dy = 0.5f*(odi[i] + emi[i]);
            float Ox = c2_*Dx - s2_*Dy,        Oy = c2_*Dy + s2_*Dx;
            odr[i] = Ex - Oy;  odi[i] = Ey + Ox;
        }
    }

    // ---- p5: stepA odd quads -> LDS (overwrites the stash slots) ----
    #pragma unroll
    for (int j0 = 0; j0 < 2; ++j0){
        float2 t1 = j0 ? twb1 : twa1;
        float2 t2 = j0 ? twb2 : twa2;
        float2 t3 = j0 ? twb3 : twa3;
        int qb = 2*lane + 1 + 128*j0;
        float2 x0 = make_float2(odr[j0],   odi[j0]);
        float2 x1 = make_float2(odr[j0+2], odi[j0+2]);
        float2 x2 = make_float2(odr[j0+4], odi[j0+4]);
        float2 x3 = make_float2(odr[j0+6], odi[j0+6]);
        fft4v(x0, x1, x2, x3);
        Z[zmap2(qb)]     = x0;
        Z[zmap2(qb+256)] = cmul(x1, t1);
        Z[zmap2(qb+512)] = cmul(x2, t2);
        Z[zmap2(qb+768)] = cmul(x3, t3);
    }

    WAVE_FENCE();
    fft_stepB_wave(Z, lane);
    WAVE_FENCE();
    fft_stepC_wave(Z, lane);

    // ---- p6: residual-X load; latency hides under barrier + gather ----
    __builtin_amdgcn_sched_barrier(0);  // don't hoist into stepB/stepC (a[16] live there)
    f32x4 xe[4], xo[4];
    #pragma unroll
    for (int i = 0; i < 4; ++i){
        int pi = tid + 256*i;
        size_t base = ((size_t)(b*2048 + 2*pi)*512 + p)*8 + c0;
        xe[i] = *(const f32x4*)(X + base);
        xo[i] = *(const f32x4*)(X + base + 4096);
    }

    __syncthreads();                 // only cross-wave handoff: final gather reads all 4 seqs
    // unpack (index reversal) + residual + float4 store
    const float sc = 0.04419417382415922f;   // sqrt(2048)/1024
    #pragma unroll
    for (int i = 0; i < 4; ++i){
        int pi = tid + 256*i;
        int zb = sig(1024 - pi);
        size_t base = ((size_t)(b*2048 + 2*pi)*512 + p)*8 + c0;
        f32x4 oe, oo;
        #pragma unroll
        for (int s = 0; s < 4; ++s){
            float2 r = Zs[s*SEQ + zb];
            oe[s] = r.x*sc + xe[i][s];
            oo[s] = r.y*sc + xo[i][s];
        }
        *(f32x4*)(OUT + base)        = oe;
        *(f32x4*)(OUT + base + 4096) = oo;
    }
}

extern "C" void kernel_launch(void* const* d_in, const int* in_sizes, int n_in,
                              void* d_out, int out_size, void* d_ws, size_t ws_size,
                              hipStream_t stream){
    (void)in_sizes; (void)n_in; (void)out_size; (void)ws_size;
    const float* x  = (const float*)d_in[0];
    const float* w1 = (const float*)d_in[1];
    const float* b1 = (const float*)d_in[2];
    const float* w2 = (const float*)d_in[3];
    const float* b2 = (const float*)d_in[4];
    float* out = (float*)d_out;
    u16* WSW = (u16*)d_ws;
    u16* S1  = (u16*)((char*)d_ws + (1 << 20));

    prep_w<<<dim3(512),  dim3(256), 0, stream>>>(w1, w2, WSW);
    fwd_fft<<<dim3(4096), dim3(256), 0, stream>>>(x, S1);
    mlp_kernel<<<dim3(4352), dim3(256), 0, stream>>>(WSW, b1, b2, S1);
    inv_fft<<<dim3(4096), dim3(256), 0, stream>>>(S1, x, out);
}